// Round 1
// baseline (534.130 us; speedup 1.0000x reference)
//
#include <hip/hip_runtime.h>
#include <stdint.h>

#define HASH_EMPTY 0xFFFFFFFFFFFFFFFFULL
#define RES_EMPTY  0x7FFFFFFF

__device__ __forceinline__ uint32_t hash_key(uint64_t k) {
    k *= 0x9E3779B97F4A7C15ULL;
    return (uint32_t)(k >> 32);
}

// ws init: last[N] = -1, hash keys = EMPTY, res[B] = INT_MAX
__global__ void init_kernel(int* __restrict__ last, unsigned long long* __restrict__ hkeys,
                            int* __restrict__ res, int N, int H, int B) {
    int t = blockIdx.x * blockDim.x + threadIdx.x;
    if (t < N) last[t] = -1;
    if (t < H) hkeys[t] = HASH_EMPTY;
    if (t < B) res[t] = RES_EMPTY;
}

// node write-order resolution (atomicMax over order) + query-key hash build
__global__ void writes_kernel(const int* __restrict__ srcID, const int* __restrict__ dstID,
                              int* __restrict__ last, unsigned long long* __restrict__ hkeys,
                              int* __restrict__ hvals, int B, int N, int H) {
    int i = blockIdx.x * blockDim.x + threadIdx.x;
    if (i < 2 * B) {
        int id = (i & 1) ? dstID[i >> 1] : srcID[i >> 1];
        atomicMax(&last[id], i);  // last write (largest order) wins
    }
    if (i < B) {
        uint64_t key = (uint64_t)(uint32_t)srcID[i] * (uint32_t)N + (uint32_t)dstID[i];
        uint32_t h = hash_key(key) & (uint32_t)(H - 1);
        while (true) {
            unsigned long long old = atomicCAS(&hkeys[h], HASH_EMPTY, (unsigned long long)key);
            if (old == HASH_EMPTY || old == (unsigned long long)key) { hvals[h] = i; break; }
            h = (h + 1) & (uint32_t)(H - 1);
        }
    }
}

// one streaming pass over all E edges: emit edge_index as float + probe query hash.
// min edge index per key via atomicMin matches stable-argsort+leftmost-searchsorted.
__global__ void edge_pass_kernel(const int* __restrict__ edge_index, float* __restrict__ out_ei,
                                 const unsigned long long* __restrict__ hkeys,
                                 const int* __restrict__ hvals, int* __restrict__ res,
                                 long long E, int N, int H) {
    long long stride = (long long)gridDim.x * blockDim.x;
    for (long long e = (long long)blockIdx.x * blockDim.x + threadIdx.x; e < E; e += stride) {
        int s = edge_index[e];
        int d = edge_index[E + e];
        out_ei[e]     = (float)s;
        out_ei[E + e] = (float)d;
        uint64_t key = (uint64_t)(uint32_t)s * (uint32_t)N + (uint32_t)d;
        uint32_t h = hash_key(key) & (uint32_t)(H - 1);
        while (true) {
            unsigned long long k = hkeys[h];
            if (k == HASH_EMPTY) break;
            if (k == (unsigned long long)key) { atomicMin(&res[hvals[h]], (int)e); break; }
            h = (h + 1) & (uint32_t)(H - 1);
        }
    }
}

// overwrite the matched edges' rows with edge_feature (after the bulk copy)
__global__ void scatter_kernel(const float* __restrict__ edge_feature, const int* __restrict__ res,
                               float* __restrict__ out_edge, int B, int F) {
    int t = blockIdx.x * blockDim.x + threadIdx.x;
    if (t >= B * F) return;
    int q = t / F;
    int f = t - q * F;
    int e = res[q];
    if (e == RES_EMPTY) return;  // mode='drop'
    out_edge[(long long)e * F + f] = edge_feature[t];
}

// x_new (gather from src/dst features for hit nodes, else G_x) + updated flags
__global__ void nodes_kernel(const float* __restrict__ G_x, const float* __restrict__ srcf,
                             const float* __restrict__ dstf, const int* __restrict__ last,
                             float* __restrict__ out_x, float* __restrict__ out_upd,
                             int N, int F) {
    int t = blockIdx.x * blockDim.x + threadIdx.x;
    int NF = N * F;
    if (t < NF) {
        int n = t / 15;          // F == 15 on this problem; fallback below if not
        if (F != 15) n = t / F;
        int f = t - n * F;
        int l = last[n];
        float v;
        if (l >= 0) {
            const float* row = (l & 1) ? dstf : srcf;
            v = row[(l >> 1) * F + f];
        } else {
            v = G_x[t];
        }
        out_x[t] = v;
    } else if (t < NF + N) {
        int n = t - NF;
        out_upd[n] = (last[n] >= 0) ? 1.0f : 0.0f;
    }
}

extern "C" void kernel_launch(void* const* d_in, const int* in_sizes, int n_in,
                              void* d_out, int out_size, void* d_ws, size_t ws_size,
                              hipStream_t stream) {
    const float* G_x         = (const float*)d_in[0];
    // d_in[1] = G_idx (arange, identity under searchsorted) — unused
    const int*   edge_index  = (const int*)d_in[2];
    const float* edge_attr   = (const float*)d_in[3];
    const int*   srcID       = (const int*)d_in[4];
    const int*   dstID       = (const int*)d_in[5];
    const float* src_feature = (const float*)d_in[6];
    const float* dst_feature = (const float*)d_in[7];
    const float* edge_feature= (const float*)d_in[8];

    const int       N = in_sizes[1];
    const long long E = (long long)in_sizes[2] / 2;
    const int       B = in_sizes[4];
    const int       F = in_sizes[0] / N;
    const int       H = 65536;   // query hash: 4x oversized vs B=16384

    float* out      = (float*)d_out;
    float* out_x    = out;                                   // [N*F]
    float* out_edge = out + (long long)N * F;                // [E*F]
    float* out_upd  = out + (long long)(N + E) * F;          // [N]
    float* out_ei   = out_upd + N;                           // [2E]

    char* ws = (char*)d_ws;
    int* last = (int*)ws;                         ws += (size_t)N * sizeof(int);
    unsigned long long* hkeys = (unsigned long long*)ws; ws += (size_t)H * sizeof(unsigned long long);
    int* hvals = (int*)ws;                        ws += (size_t)H * sizeof(int);
    int* res = (int*)ws;

    const int T = 256;
    int initN = N > H ? N : H; if (B > initN) initN = B;

    hipLaunchKernelGGL(init_kernel, dim3((initN + T - 1) / T), dim3(T), 0, stream,
                       last, hkeys, res, N, H, B);
    hipLaunchKernelGGL(writes_kernel, dim3((2 * B + T - 1) / T), dim3(T), 0, stream,
                       srcID, dstID, last, hkeys, hvals, B, N, H);
    // bulk copy edge_attr -> out (scatter overwrites matched rows afterwards)
    hipMemcpyAsync(out_edge, edge_attr, (size_t)E * F * sizeof(float),
                   hipMemcpyDeviceToDevice, stream);
    hipLaunchKernelGGL(edge_pass_kernel, dim3(2048), dim3(T), 0, stream,
                       edge_index, out_ei, hkeys, hvals, res, E, N, H);
    hipLaunchKernelGGL(scatter_kernel, dim3((B * F + T - 1) / T), dim3(T), 0, stream,
                       edge_feature, res, out_edge, B, F);
    hipLaunchKernelGGL(nodes_kernel, dim3(((long long)N * (F + 1) + T - 1) / T), dim3(T), 0, stream,
                       G_x, src_feature, dst_feature, last, out_x, out_upd, N, F);
}